// Round 7
// baseline (809.023 us; speedup 1.0000x reference)
//
#include <hip/hip_runtime.h>
#include <math.h>

#define BATCH 32
#define NN 1024
#define MM 1024
#define LPATH (NN + MM - 1)     // 2047

// ---------------- Persistent paired-band wavefront geometry ----------------
// 8x8 grid of 128x128 panels per batch. Block = (batch-PAIR p, band r):
// one wave carries TWO independent batches (2p, 2p+1) through band r
// simultaneously -- two independent DP chains fill each other's VALU latency
// bubbles (single-wave in-order issue was measured at ~5 cyc/instr, ILP~1).
// 128 blocks; bottom rows cross bands via global memory + one flag per
// (pair, band, panel).
#define PB 128                  // panel rows
#define PQ 128                  // panel cols
#define GB 8                    // bands
#define GH 8                    // panel columns
#define PAN_WORDS 1536          // 24 sblk x 64 lanes (4 bits/step/lane)
#define BAT_WORDS (GB * GH * PAN_WORDS)               // 98304 words / batch
#define DEC_WORDS ((size_t)BATCH * BAT_WORDS)         // 3,145,728 words
#define BR_OFFW DEC_WORDS                             // brow planes (9x1024/b)
#define BRPL (9 * 1024)
#define FL_OFFW (BR_OFFW + (size_t)BATCH * BRPL)      // flags
#define WS_WORDS (FL_OFFW + (size_t)BATCH * 64)
#define REQ_WS_NEW (WS_WORDS * 4)                     // ~13.8 MB

// Legacy (proven 557us) path requirement
#define DEC_WORDS_PER_BATCH ((NN / 4) * (MM / 4))     // 65536
#define REQ_WS ((size_t)BATCH * DEC_WORDS_PER_BATCH * 4)   // 8 MB

__global__ void init_kernel(float* out) { out[0] = 0.0f; }

// ---- init: zero flags + out (runs each graph replay) ------------------------
__global__ void init3(unsigned* __restrict__ wsu, float* __restrict__ out)
{
    const int t = threadIdx.x;
    if (t == 0) out[0] = 0.0f;
    for (int i = t; i < BATCH * 64; i += 256) wsu[FL_OFFW + i] = 0u;
}

__device__ __forceinline__ float wave_shr1(float v)
{
    return __int_as_float(__builtin_amdgcn_update_dpp(
        __float_as_int(v), __float_as_int(v), 0x138, 0xF, 0xF, false));
}

// ---- Persistent DP kernel: 128 blocks (16 pairs x 8 bands) x 64 threads -----
// Per-stream inner math is VERBATIM the R5/R6-verified body (absmax=0);
// streams A (batch 2p) and B (batch 2p+1) are interleaved instruction-by-
// instruction in one straight-line unrolled body.
__global__ __launch_bounds__(64, 1) void dtw_dp2(
    const float* __restrict__ preds, const float* __restrict__ targs,
    unsigned* __restrict__ wsu)
{
    const int blk = blockIdx.x;
    const int p = blk >> 3, r = blk & 7;
    const int b0 = 2 * p, b1 = 2 * p + 1;
    const int l = threadIdx.x;
    const float INF = __builtin_inff();

    __shared__ __align__(16) float txA0[1160], tyA0[1160];
    __shared__ __align__(16) float txA1[1160], tyA1[1160];
    __shared__ __align__(16) float TL0[208], TL1[208];
    __shared__ __align__(16) float botL0[128], botL1[128];

    // pads
    for (int i = l; i < 64; i += 64) {
        txA0[i] = 0.f; tyA0[i] = 0.f; txA1[i] = 0.f; tyA1[i] = 0.f;
    }
    for (int i = 1087 + l; i < 1160; i += 64) {
        txA0[i] = 0.f; tyA0[i] = 0.f; txA1[i] = 0.f; tyA1[i] = 0.f;
    }
    TL0[128 + l] = INF; TL1[128 + l] = INF;
    if (l < 16) { TL0[192 + l] = INF; TL1[192 + l] = INF; }
    if (r == 0) {
        TL0[l] = INF; TL0[64 + l] = INF;
        TL1[l] = INF; TL1[64 + l] = INF;
    }

    // stage both targ streams (col j's basis x,y at [63+j])
    {
        const float4* tg40 = (const float4*)targs + (size_t)b0 * MM;
        const float4* tg41 = (const float4*)targs + (size_t)b1 * MM;
        for (int j = l; j < MM; j += 64) {
            const float4 v = tg40[j];
            txA0[63 + j] = v.x; tyA0[63 + j] = v.y;
            const float4 w = tg41[j];
            txA1[63 + j] = w.x; tyA1[63 + j] = w.y;
        }
    }

    // pred rows (2 per lane per stream)
    const float4* pp40 = (const float4*)preds + (size_t)b0 * NN + r * PB;
    const float4* pp41 = (const float4*)preds + (size_t)b1 * NN + r * PB;
    const float4 a0 = pp40[2 * l], a1 = pp40[2 * l + 1];
    const float4 c0v = pp41[2 * l], c1v = pp41[2 * l + 1];
    const float pxA0 = a0.x, pyA0 = a0.y, pxA1 = a1.x, pyA1 = a1.y;
    const float pxB0 = c0v.x, pyB0 = c0v.y, pxB1 = c1v.x, pyB1 = c1v.y;

    unsigned* __restrict__ browI0 = wsu + BR_OFFW + (size_t)b0 * BRPL;
    unsigned* __restrict__ browI1 = wsu + BR_OFFW + (size_t)b1 * BRPL;
    unsigned* __restrict__ flagP = wsu + FL_OFFW + (size_t)p * 64;

    float D0A = INF, D1A = INF, D0B = INF, D1B = INF;
    __syncthreads();

    for (int c = 0; c < GH; ++c) {
        float tlm1A, tlm1B;
        if (r > 0) {
            const int fi = (r - 1) * 8 + c;
            while (__hip_atomic_load(&flagP[fi], __ATOMIC_ACQUIRE,
                                     __HIP_MEMORY_SCOPE_AGENT) == 0u)
                __builtin_amdgcn_s_sleep(1);
            const unsigned* bp0 = browI0 + (size_t)r * 1024 + c * PQ;
            const unsigned* bp1 = browI1 + (size_t)r * 1024 + c * PQ;
            TL0[2 * l] = __int_as_float(__hip_atomic_load((unsigned*)&bp0[2 * l],
                             __ATOMIC_RELAXED, __HIP_MEMORY_SCOPE_AGENT));
            TL0[2 * l + 1] = __int_as_float(__hip_atomic_load((unsigned*)&bp0[2 * l + 1],
                             __ATOMIC_RELAXED, __HIP_MEMORY_SCOPE_AGENT));
            TL1[2 * l] = __int_as_float(__hip_atomic_load((unsigned*)&bp1[2 * l],
                             __ATOMIC_RELAXED, __HIP_MEMORY_SCOPE_AGENT));
            TL1[2 * l + 1] = __int_as_float(__hip_atomic_load((unsigned*)&bp1[2 * l + 1],
                             __ATOMIC_RELAXED, __HIP_MEMORY_SCOPE_AGENT));
            tlm1A = (c == 0) ? INF
                  : __int_as_float(__hip_atomic_load((unsigned*)&bp0[-1],
                        __ATOMIC_RELAXED, __HIP_MEMORY_SCOPE_AGENT));
            tlm1B = (c == 0) ? INF
                  : __int_as_float(__hip_atomic_load((unsigned*)&bp1[-1],
                        __ATOMIC_RELAXED, __HIP_MEMORY_SCOPE_AGENT));
        } else {
            tlm1A = (c == 0) ? 0.0f : INF;
            tlm1B = (c == 0) ? 0.0f : INF;
        }
        const float shA1 = wave_shr1(D1A), shB1 = wave_shr1(D1B);
        const float dg0initA = (l == 0) ? tlm1A : ((c == 0) ? INF : shA1);
        const float dg0initB = (l == 0) ? tlm1B : ((c == 0) ? INF : shB1);

        unsigned* __restrict__ decP0 = wsu + (size_t)b0 * BAT_WORDS
                                     + (size_t)(r * GH + c) * PAN_WORDS + l;
        unsigned* __restrict__ decP1 = wsu + (size_t)b1 * BAT_WORDS
                                     + (size_t)(r * GH + c) * PAN_WORDS + l;
        const int cb = 63 + c * PQ;

        float txbA[8], tybA[8], txbB[8], tybB[8];
        #pragma unroll
        for (int k = 0; k < 4; ++k) {
            txbA[k] = txA0[cb + k - l]; tybA[k] = tyA0[cb + k - l];
            txbB[k] = txA1[cb + k - l]; tybB[k] = tyA1[cb + k - l];
        }
        float up0prevA = INF, up0prevB = INF;

        for (int it = 0; it < 24; ++it) {
            const int s0 = it * 8;
            const float4 TA4a = *(const float4*)&TL0[s0];
            const float4 TA4b = *(const float4*)&TL0[s0 + 4];
            const float TvA[8] = {TA4a.x, TA4a.y, TA4a.z, TA4a.w,
                                  TA4b.x, TA4b.y, TA4b.z, TA4b.w};
            const float4 TB4a = *(const float4*)&TL1[s0];
            const float4 TB4b = *(const float4*)&TL1[s0 + 4];
            const float TvB[8] = {TB4a.x, TB4a.y, TB4a.z, TB4a.w,
                                  TB4b.x, TB4b.y, TB4b.z, TB4b.w};
            unsigned wordA = 0, wordB = 0;
            #pragma unroll
            for (int k = 0; k < 8; ++k) {
                const int s = s0 + k;
                const int jq = s - l;
                txbA[(k + 4) & 7] = txA0[cb + jq + 4];
                tybA[(k + 4) & 7] = tyA0[cb + jq + 4];
                txbB[(k + 4) & 7] = txA1[cb + jq + 4];
                tybB[(k + 4) & 7] = tyA1[cb + jq + 4];
                const bool act = (jq >= 0) && (jq < PQ);
                // ---- stream A (batch b0), verbatim math ----
                const float shA = wave_shr1(D1A);
                const float up0A = (l == 0) ? TvA[k] : shA;
                const float dg0A = (jq == 0) ? dg0initA : up0prevA;
                const float txa = txbA[k], tya = tybA[k];
                const float dxA0 = pxA0 - txa, dyA0 = pyA0 - tya;
                const float cA0 = __builtin_amdgcn_sqrtf(dxA0 * dxA0 + dyA0 * dyA0);
                const float mnA0 = fminf(dg0A, fminf(up0A, D0A));
                const float DA0n = cA0 + mnA0;
                const unsigned mA0 = (mnA0 == dg0A) ? 0u : ((mnA0 == up0A) ? 1u : 2u);
                const float dgA1 = D0A;
                const float dxA1 = pxA1 - txa, dyA1 = pyA1 - tya;
                const float cA1 = __builtin_amdgcn_sqrtf(dxA1 * dxA1 + dyA1 * dyA1);
                const float mnA1 = fminf(dgA1, fminf(DA0n, D1A));
                const float DA1n = cA1 + mnA1;
                const unsigned mA1 = (mnA1 == dgA1) ? 0u : ((mnA1 == DA0n) ? 1u : 2u);
                wordA |= (mA0 | (mA1 << 2)) << (4 * k);
                // ---- stream B (batch b1), verbatim math ----
                const float shB = wave_shr1(D1B);
                const float up0B = (l == 0) ? TvB[k] : shB;
                const float dg0B = (jq == 0) ? dg0initB : up0prevB;
                const float txbv = txbB[k], tybv = tybB[k];
                const float dxB0 = pxB0 - txbv, dyB0 = pyB0 - tybv;
                const float cB0 = __builtin_amdgcn_sqrtf(dxB0 * dxB0 + dyB0 * dyB0);
                const float mnB0 = fminf(dg0B, fminf(up0B, D0B));
                const float DB0n = cB0 + mnB0;
                const unsigned mB0 = (mnB0 == dg0B) ? 0u : ((mnB0 == up0B) ? 1u : 2u);
                const float dgB1 = D0B;
                const float dxB1 = pxB1 - txbv, dyB1 = pyB1 - tybv;
                const float cB1 = __builtin_amdgcn_sqrtf(dxB1 * dxB1 + dyB1 * dyB1);
                const float mnB1 = fminf(dgB1, fminf(DB0n, D1B));
                const float DB1n = cB1 + mnB1;
                const unsigned mB1 = (mnB1 == dgB1) ? 0u : ((mnB1 == DB0n) ? 1u : 2u);
                wordB |= (mB0 | (mB1 << 2)) << (4 * k);
                // ---- commit ----
                if (act) { D0A = DA0n; D1A = DA1n; D0B = DB0n; D1B = DB1n; }
                up0prevA = up0A; up0prevB = up0B;
                if (l == 63 && act) { botL0[jq] = DA1n; botL1[jq] = DB1n; }
            }
            decP0[it * 64] = wordA;
            decP1[it * 64] = wordB;
        }

        if (r < GB - 1) {
            unsigned* bw0 = browI0 + (size_t)(r + 1) * 1024 + c * PQ;
            unsigned* bw1 = browI1 + (size_t)(r + 1) * 1024 + c * PQ;
            __hip_atomic_store(&bw0[2 * l], __float_as_int(botL0[2 * l]),
                               __ATOMIC_RELAXED, __HIP_MEMORY_SCOPE_AGENT);
            __hip_atomic_store(&bw0[2 * l + 1], __float_as_int(botL0[2 * l + 1]),
                               __ATOMIC_RELAXED, __HIP_MEMORY_SCOPE_AGENT);
            __hip_atomic_store(&bw1[2 * l], __float_as_int(botL1[2 * l]),
                               __ATOMIC_RELAXED, __HIP_MEMORY_SCOPE_AGENT);
            __hip_atomic_store(&bw1[2 * l + 1], __float_as_int(botL1[2 * l + 1]),
                               __ATOMIC_RELAXED, __HIP_MEMORY_SCOPE_AGENT);
            __threadfence();
            if (l == 0)
                __hip_atomic_store(&flagP[r * 8 + c], 1u, __ATOMIC_RELEASE,
                                   __HIP_MEMORY_SCOPE_AGENT);
        }
    }
}

// ---- Backtrack + loss: 32 blocks x 256 threads ------------------------------
// R7 change: 3-neighbor word prefetch. All within-panel word transitions go
// to widx-1, widx-64 or widx-65; prefetching them at word arrival hides the
// ~200-cycle L2 latency under the walk's VALU. Walk logic/bit extraction
// verbatim from R5/R6 (absmax=0).
__global__ __launch_bounds__(256, 1) void dtw_bt(
    const float* __restrict__ preds, const float* __restrict__ targs,
    const float* __restrict__ subcoef, const float* __restrict__ ws,
    float* __restrict__ out)
{
    const int b = blockIdx.x, t = threadIdx.x;
    __shared__ float pxA[NN], pyA[NN], txA[MM], tyA[MM];   // 16 KB
    __shared__ unsigned path[2048];                        // 8 KB
    __shared__ int sN;
    __shared__ float wsum[4];

    for (int it = 0; it < 4; ++it) {
        const int idx = it * 256 + t;
        const float4 p4 = ((const float4*)preds)[(size_t)b * NN + idx];
        pxA[idx] = p4.x; pyA[idx] = p4.y;
        const float4 t4 = ((const float4*)targs)[(size_t)b * MM + idx];
        txA[idx] = t4.x; tyA[idx] = t4.y;
    }
    __syncthreads();

    if (t == 0) {
        const unsigned* __restrict__ decB =
            (const unsigned*)ws + (size_t)b * BAT_WORDS;
        int i = NN - 1, j = MM - 1, n = 0;
        int cwidx; unsigned cw, wA, wB, wC;
        {
            const int ll = (i & 127) >> 1;
            const int ss = ll + (j & 127);
            cwidx = (((i >> 7) << 3) + (j >> 7)) * PAN_WORDS + (ss >> 3) * 64 + ll;
            cw = decB[cwidx];
            wA = decB[(cwidx >= 1) ? cwidx - 1 : 0];
            wB = decB[(cwidx >= 64) ? cwidx - 64 : 0];
            wC = decB[(cwidx >= 65) ? cwidx - 65 : 0];
        }
        while (true) {
            path[n++] = ((unsigned)i << 16) | (unsigned)j;
            if ((i | j) == 0) break;
            const int ss = ((i & 127) >> 1) + (j & 127);
            const unsigned m = (cw >> ((ss & 7) * 4 + (i & 1) * 2)) & 3u;
            i -= (m != 2u); j -= (m != 1u);
            const int ll2 = (i & 127) >> 1;
            const int ss2 = ll2 + (j & 127);
            const int widx = (((i >> 7) << 3) + (j >> 7)) * PAN_WORDS
                           + (ss2 >> 3) * 64 + ll2;
            if (widx != cwidx) {
                cw = (widx == cwidx - 1) ? wA
                   : (widx == cwidx - 64) ? wB
                   : (widx == cwidx - 65) ? wC
                   : decB[widx];
                cwidx = widx;
                wA = decB[(widx >= 1) ? widx - 1 : 0];
                wB = decB[(widx >= 64) ? widx - 64 : 0];
                wC = decB[(widx >= 65) ? widx - 65 : 0];
            }
        }
        sN = n;
    }
    __syncthreads();

    const float sc0 = subcoef[0], sc1 = subcoef[1];
    const int n = sN;
    float acc = 0.0f;
    for (int p = t; p < n; p += 256) {
        const unsigned e = path[p];
        const int i = (int)(e >> 16), j = (int)(e & 0xffffu);
        acc += fabsf(pxA[i] - txA[j]) * sc0 + fabsf(pyA[i] - tyA[j]) * sc1;
    }
    #pragma unroll
    for (int o = 32; o > 0; o >>= 1) acc += __shfl_down(acc, o);
    if ((t & 63) == 0) wsum[t >> 6] = acc;
    __syncthreads();
    if (t == 0) atomicAdd(out, (wsum[0] + wsum[1]) + (wsum[2] + wsum[3]));
}

// =================== Legacy proven path (557us, needs 8MB) ===================
__device__ inline void bt_walk4(const unsigned* __restrict__ sdec, int roff,
                                int iLow, int& i, int& j, int& n,
                                unsigned* __restrict__ path)
{
    int ri = i >> 2, jc = j >> 2;
    unsigned w = sdec[(ri - roff) * 256 + jc];
    while (true) {
        const int base = (ri - roff) * 256 + jc;
        const unsigned wl = sdec[(jc > 0)    ? base - 1   : base];
        const unsigned wu = sdec[(ri > roff) ? base - 256 : base];
        const unsigned wd = sdec[(ri > roff && jc > 0) ? base - 257 : base];
        bool done = false, susp = false;
        while (true) {
            path[n++] = ((unsigned)i << 16) | (unsigned)j;
            if ((i | j) == 0) { done = true; break; }
            const unsigned m = (w >> (((i & 3) * 4 + (j & 3)) * 2)) & 3u;
            i -= (m != 2u); j -= (m != 1u);
            if (i < iLow) { susp = true; break; }
            if ((i >> 2) != ri || (j >> 2) != jc) break;
        }
        if (done || susp) break;
        const int nri = i >> 2, njc = j >> 2;
        w = (nri == ri) ? wl : ((njc == jc) ? wu : wd);
        ri = nri; jc = njc;
    }
}

#define RRL 4
#define CCL 4
#define LANES 64
#define NWAVE 4
#define TPBL (MM / 4)
#define NSUP (TPBL + LANES - 1)
#define LAG 72
#define TOTL (NSUP + (NWAVE - 1) * LAG)
#define DEPTH 32

__global__ __launch_bounds__(256, 1) void dtw_fused_legacy(
    const float* __restrict__ preds, const float* __restrict__ targs,
    const float* __restrict__ subcoef, unsigned* __restrict__ dec,
    float* __restrict__ out)
{
    const int b = blockIdx.x, t = threadIdx.x;
    const int l = t & 63, w = t >> 6;
    const float INF = __builtin_inff();

    __shared__ float pxA[NN], pyA[NN], txA[MM], tyA[MM];
    __shared__ float4 ring[NWAVE - 1][DEPTH];
    __shared__ unsigned sdec[128 * 256];
    __shared__ unsigned path[LPATH + 1];
    __shared__ int sI, sJ, sN;
    __shared__ float wsum[NWAVE];

    for (int it = 0; it < NN / 256; ++it) {
        const int idx = it * 256 + t;
        const float4 p4 = ((const float4*)preds)[(size_t)b * NN + idx];
        pxA[idx] = p4.x; pyA[idx] = p4.y;
        const float4 t4 = ((const float4*)targs)[(size_t)b * MM + idx];
        txA[idx] = t4.x; tyA[idx] = t4.y;
    }
    __syncthreads();

    const int i0 = (w << 8) + (l << 2);
    const float4 px4 = ((const float4*)pxA)[i0 >> 2];
    const float4 py4 = ((const float4*)pyA)[i0 >> 2];
    const float px[RRL] = {px4.x, px4.y, px4.z, px4.w};
    const float py[RRL] = {py4.x, py4.y, py4.z, py4.w};
    unsigned* __restrict__ decW =
        dec + (size_t)b * DEC_WORDS_PER_BATCH + ((size_t)w << 14) + (size_t)l;

    float Dp[RRL], Dbot[CCL], bv[CCL];
    #pragma unroll
    for (int r = 0; r < RRL; ++r) Dp[r] = INF;
    #pragma unroll
    for (int c = 0; c < CCL; ++c) { Dbot[c] = INF; bv[c] = INF; }
    float bndRet = (w == 0 && l == 0) ? 0.0f : INF;
    float4 gcur = make_float4(INF, INF, INF, INF);
    float4 tx4 = ((const float4*)txA)[0], ty4 = ((const float4*)tyA)[0];
    const float4* __restrict__ ringR = ring[(w > 0) ? (w - 1) : 0];

    for (int u = 0; u < TOTL; ++u) {
        const int ul = u - LAG * w;
        if (l == 0) {
            const bool gb = (w > 0) && (ul >= 0) && (ul < TPBL);
            bv[0] = gb ? gcur.x : INF; bv[1] = gb ? gcur.y : INF;
            bv[2] = gb ? gcur.z : INF; bv[3] = gb ? gcur.w : INF;
        }
        const bool act = (ul >= l) && (ul < l + TPBL);
        if (act) {
            const float cx[CCL] = {tx4.x, tx4.y, tx4.z, tx4.w};
            const float cy[CCL] = {ty4.x, ty4.y, ty4.z, ty4.w};
            float cost[RRL][CCL];
            #pragma unroll
            for (int c = 0; c < CCL; ++c)
                #pragma unroll
                for (int r = 0; r < RRL; ++r) {
                    const float dx = px[r] - cx[c], dy = py[r] - cy[c];
                    cost[r][c] = __builtin_amdgcn_sqrtf(dx * dx + dy * dy);
                }
            unsigned word = 0;
            #pragma unroll
            for (int c = 0; c < CCL; ++c) {
                float up = bv[c];
                float dg = (c == 0) ? bndRet : bv[c - 1];
                #pragma unroll
                for (int r = 0; r < RRL; ++r) {
                    const float lf = Dp[r];
                    const unsigned m = (dg <= up && dg <= lf) ? 0u
                                     : ((up <= lf) ? 1u : 2u);
                    const float D = cost[r][c] + fminf(dg, fminf(up, lf));
                    word |= m << ((r * 4 + c) * 2);
                    dg = lf; up = D; Dp[r] = D;
                }
                Dbot[c] = up;
            }
            decW[(ul & 255) << 6] = word;
            if (l == LANES - 1 && w < NWAVE - 1)
                ring[w][ul & (DEPTH - 1)] =
                    make_float4(Dbot[0], Dbot[1], Dbot[2], Dbot[3]);
        }
        bndRet = bv[CCL - 1];
        #pragma unroll
        for (int c = 0; c < CCL; ++c) bv[c] = __shfl_up(Dbot[c], 1);
        const int un = ul + 1;
        if (un >= l && un < l + TPBL) {
            const int jn = CCL * (un - l);
            tx4 = ((const float4*)txA)[jn >> 2];
            ty4 = ((const float4*)tyA)[jn >> 2];
        }
        if (w > 0 && un >= 0 && un < TPBL)
            gcur = ringR[(un + 63) & (DEPTH - 1)];
        if ((u & 7) == 7) __syncthreads();
    }

    __threadfence_block();
    __syncthreads();

    const unsigned* __restrict__ decB = dec + (size_t)b * DEC_WORDS_PER_BATCH;
    {
        const uint4* g4 = (const uint4*)(decB + 32768);
        for (int k = t; k < 8192; k += 256) {
            const uint4 v = g4[k];
            const int kb = k << 2;
            const int wv = kb >> 14;
            const int rem = kb & 16383;
            const int q = rem >> 6;
            const int lb = rem & 63;
            const unsigned wd[4] = {v.x, v.y, v.z, v.w};
            #pragma unroll
            for (int e = 0; e < 4; ++e) {
                const int ll = lb + e;
                const int row = (wv << 6) + ll;
                const int jc = (q - ll) & 255;
                sdec[(row << 8) + jc] = wd[e];
            }
        }
    }
    __syncthreads();
    if (t == 0) {
        int i = NN - 1, j = MM - 1, n = 0;
        bt_walk4(sdec, 128, 512, i, j, n, path);
        sI = i; sJ = j; sN = n;
    }
    __syncthreads();
    {
        const uint4* g4 = (const uint4*)decB;
        for (int k = t; k < 8192; k += 256) {
            const uint4 v = g4[k];
            const int kb = k << 2;
            const int wv = kb >> 14;
            const int rem = kb & 16383;
            const int q = rem >> 6;
            const int lb = rem & 63;
            const unsigned wd[4] = {v.x, v.y, v.z, v.w};
            #pragma unroll
            for (int e = 0; e < 4; ++e) {
                const int ll = lb + e;
                const int row = (wv << 6) + ll;
                const int jc = (q - ll) & 255;
                sdec[(row << 8) + jc] = wd[e];
            }
        }
    }
    __syncthreads();
    if (t == 0) {
        int i = sI, j = sJ, n = sN;
        bt_walk4(sdec, 0, 0, i, j, n, path);
        sN = n;
    }
    __syncthreads();

    const float sc0 = subcoef[0], sc1 = subcoef[1];
    const int n = sN;
    float acc = 0.0f;
    for (int p = t; p < n; p += 256) {
        const unsigned e = path[p];
        const int i = (int)(e >> 16), j = (int)(e & 0xffffu);
        acc += fabsf(pxA[i] - txA[j]) * sc0 + fabsf(pyA[i] - tyA[j]) * sc1;
    }
    #pragma unroll
    for (int o = 32; o > 0; o >>= 1) acc += __shfl_down(acc, o);
    if ((t & 63) == 0) wsum[t >> 6] = acc;
    __syncthreads();
    if (t == 0) atomicAdd(out, (wsum[0] + wsum[1]) + (wsum[2] + wsum[3]));
}

// ------------- Fallback (only if ws too small for everything) ----------------
__global__ __launch_bounds__(256) void dtw_fallback(
    const float* __restrict__ preds, const float* __restrict__ targs,
    const float* __restrict__ subcoef, unsigned* __restrict__ dec,
    float* __restrict__ out)
{
    const int b = blockIdx.x;
    const int t = threadIdx.x;
    const float INF = __builtin_inff();
    __shared__ float px[NN], py[NN];
    __shared__ float txy[2 * MM];
    __shared__ float bbuf[2][256];

    for (int it = 0; it < NN / 256; ++it) {
        const int idx = it * 256 + t;
        const float4 p4 = ((const float4*)preds)[(size_t)b * NN + idx];
        px[idx] = p4.x; py[idx] = p4.y;
        const float4 t4 = ((const float4*)targs)[(size_t)b * MM + idx];
        txy[2 * idx] = t4.x; txy[2 * idx + 1] = t4.y;
    }
    bbuf[0][t] = INF; bbuf[1][t] = INF;
    __syncthreads();

    float pxr[4], pyr[4], Dp[4];
    #pragma unroll
    for (int r = 0; r < 4; ++r) {
        pxr[r] = px[4 * t + r]; pyr[r] = py[4 * t + r]; Dp[r] = INF;
    }
    float dgB = (t == 0) ? 0.0f : INF;
    unsigned packed = 0;
    unsigned* decB = dec + (size_t)b * 65536;
    for (int s = 0; s < MM + 255; ++s) {
        const int j = s - t;
        const float upB = (t == 0) ? INF : bbuf[(s + 1) & 1][t - 1];
        if (j >= 0 && j < MM) {
            const float txj = txy[2 * j], tyj = txy[2 * j + 1];
            float up = upB, dg = dgB;
            unsigned mbits = 0;
            #pragma unroll
            for (int r = 0; r < 4; ++r) {
                const float dx = pxr[r] - txj, dy = pyr[r] - tyj;
                const float c = sqrtf(dx * dx + dy * dy);
                const float lf = Dp[r];
                const unsigned m = (dg <= up && dg <= lf) ? 0u
                                 : ((up <= lf) ? 1u : 2u);
                mbits |= m << (r * 8 + (j & 3) * 2);
                const float Dc = c + fminf(up, fminf(dg, lf));
                dg = lf; up = Dc; Dp[r] = Dc;
            }
            packed |= mbits;
            if ((j & 3) == 3) { decB[(unsigned)t * 256 + (j >> 2)] = packed; packed = 0; }
            bbuf[s & 1][t] = Dp[3];
        }
        dgB = upB;
        __syncthreads();
    }
    __threadfence_block();
    __syncthreads();
    if (t == 0) {
        const float sc0 = subcoef[0], sc1 = subcoef[1];
        int i = NN - 1, jj = MM - 1;
        float loss = 0.0f;
        int ti = i >> 2, tj = jj >> 2;
        unsigned wv = decB[ti * 256 + tj];
        while (true) {
            const int tjl = (tj > 0) ? tj - 1 : 0;
            const int til = (ti > 0) ? ti - 1 : 0;
            const unsigned wl = decB[ti * 256 + tjl];
            const unsigned wu = decB[til * 256 + tj];
            const unsigned wd = decB[til * 256 + tjl];
            bool done = false;
            while (true) {
                loss += fabsf(px[i] - txy[2 * jj]) * sc0
                      + fabsf(py[i] - txy[2 * jj + 1]) * sc1;
                if ((i | jj) == 0) { done = true; break; }
                const unsigned m = (wv >> (((i & 3) * 4 + (jj & 3)) * 2)) & 3u;
                i -= (m != 2u); jj -= (m != 1u);
                if ((i >> 2) != ti || (jj >> 2) != tj) break;
            }
            if (done) break;
            const int nti = i >> 2, ntj = jj >> 2;
            wv = (nti == ti) ? wl : ((ntj == tj) ? wu : wd);
            ti = nti; tj = ntj;
        }
        atomicAdd(out, loss);
    }
}

extern "C" void kernel_launch(void* const* d_in, const int* in_sizes, int n_in,
                              void* d_out, int out_size, void* d_ws, size_t ws_size,
                              hipStream_t stream) {
    const float* preds   = (const float*)d_in[0];
    const float* targs   = (const float*)d_in[1];
    const float* subcoef = (const float*)d_in[2];
    float* out = (float*)d_out;

    if (ws_size >= REQ_WS_NEW) {
        unsigned* wsu = (unsigned*)d_ws;
        init3<<<1, 256, 0, stream>>>(wsu, out);
        dtw_dp2<<<(BATCH / 2) * GB, 64, 0, stream>>>(preds, targs, wsu);
        dtw_bt<<<BATCH, 256, 0, stream>>>(preds, targs, subcoef,
                                          (const float*)d_ws, out);
    } else if (ws_size >= REQ_WS) {
        unsigned* dec = (unsigned*)d_ws;
        init_kernel<<<1, 1, 0, stream>>>(out);
        dtw_fused_legacy<<<BATCH, 256, 0, stream>>>(preds, targs, subcoef, dec, out);
    } else {
        unsigned* dec = (unsigned*)d_ws;
        init_kernel<<<1, 1, 0, stream>>>(out);
        dtw_fallback<<<BATCH, 256, 0, stream>>>(preds, targs, subcoef, dec, out);
    }
}

// Round 8
// 674.059 us; speedup vs baseline: 1.2002x; 1.2002x over previous
//
#include <hip/hip_runtime.h>
#include <math.h>

#define BATCH 32
#define NN 1024
#define MM 1024
#define LPATH (NN + MM - 1)     // 2047

// ---------------- R8: fused band-sweep geometry ----------------
// Band = 128 rows (block, 1 wave; lane owns rows 2l, 2l+1). Each band sweeps
// ALL 1024 cols in ONE skewed pass: step u (0..1087), lane l handles col
// jq = u - l. 32 batches x 8 bands = 256 blocks. Inter-band boundary (bottom
// row) flows via global memory in 32-col chunks, signalled by a monotone
// per-(batch,band) counter: producer publishes chunk c-2 at end of superblock
// c (lane63 has finished col 32c-32 by then); consumer stages chunk c+1 at
// end of its superblock c (needs producer ~96 steps ahead -- vs 192 in R6).
#define PB 128
#define GB 8
#define SB 34                   // superblocks of 32 steps (1088 steps)
#define BAND_WORDS (136 * 64)   // 8704 decision words per band
#define BAT_WORDS3 (GB * BAND_WORDS)                  // 69632 words / batch
#define DEC3_WORDS ((size_t)BATCH * BAT_WORDS3)       // 2,228,224 words
#define BR3_OFFW DEC3_WORDS                           // bottom-row planes
#define BR3_SZ ((size_t)BATCH * GB * 1024)            // 262,144 words
#define CNT_OFFW (BR3_OFFW + BR3_SZ)                  // counters (b,r)
#define WS3_WORDS (CNT_OFFW + BATCH * GB)
#define REQ_WS3 (WS3_WORDS * 4)                       // ~9.96 MB

// Legacy (proven 557us) path requirement
#define DEC_WORDS_PER_BATCH ((NN / 4) * (MM / 4))     // 65536
#define REQ_WS ((size_t)BATCH * DEC_WORDS_PER_BATCH * 4)   // 8 MB

__global__ void init_kernel(float* out) { out[0] = 0.0f; }

// ---- init: zero counters + out (runs each graph replay) ---------------------
__global__ void init4(unsigned* __restrict__ wsu, float* __restrict__ out)
{
    const int t = threadIdx.x;
    if (t == 0) out[0] = 0.0f;
    if (t < BATCH * GB) wsu[CNT_OFFW + t] = 0u;
}

__device__ __forceinline__ float wave_shr1(float v)
{
    return __int_as_float(__builtin_amdgcn_update_dpp(
        __float_as_int(v), __float_as_int(v), 0x138, 0xF, 0xF, false));
}

// ---- Fused-sweep DP: 256 blocks (32 batches x 8 bands) x 64 threads ---------
// Per-cell math VERBATIM from the R5/R6-verified body (absmax=0). Changes:
//  - one continuous 1088-step sweep (skew paid once, not per panel)
//  - tx/ty prefetch batched per 8-step block, one block ahead (no per-step
//    LDS read on the dependency chain)
//  - 32-col chunk handshake via monotone counter (lag ~96 steps, was 192)
__global__ __launch_bounds__(64, 1) void dtw_dp3(
    const float* __restrict__ preds, const float* __restrict__ targs,
    unsigned* __restrict__ wsu)
{
    const int blk = blockIdx.x;
    const int b = blk >> 3, r = blk & 7;
    const int l = threadIdx.x;
    const float INF = __builtin_inff();

    __shared__ __align__(16) float txA[1160], tyA[1160];  // skew-padded stream
    __shared__ __align__(16) float TLb[2][32];            // top-row chunk dbuf
    __shared__ float botL[64];                            // bottom-row ring

    // pads: low [0,63) (jq<0) and high [1087,1160) (prefetch overrun)
    txA[l] = 0.f; tyA[l] = 0.f;
    for (int i = 1087 + l; i < 1160; i += 64) { txA[i] = 0.f; tyA[i] = 0.f; }
    if (l < 32) { TLb[0][l] = INF; TLb[1][l] = INF; }

    // stage targ cols (col j basis x,y at [63+j])
    {
        const float4* tg4 = (const float4*)targs + (size_t)b * MM;
        for (int j = l; j < MM; j += 64) {
            const float4 v = tg4[j];
            txA[63 + j] = v.x; tyA[63 + j] = v.y;
        }
    }
    // pred rows 2l, 2l+1 of this band
    const float4* pp4 = (const float4*)preds + (size_t)b * NN + r * PB;
    const float4 p0 = pp4[2 * l], p1 = pp4[2 * l + 1];
    const float px0 = p0.x, py0 = p0.y, px1 = p1.x, py1 = p1.y;

    unsigned* __restrict__ decBand =
        wsu + (size_t)b * BAT_WORDS3 + (size_t)r * BAND_WORDS;
    float* browAll = (float*)(wsu + BR3_OFFW);
    const float* browPrev = browAll + ((size_t)b * GB + ((r > 0) ? r - 1 : 0)) * 1024;
    float* browMine = browAll + ((size_t)b * GB + r) * 1024;
    unsigned* cntPrev = wsu + CNT_OFFW + b * GB + ((r > 0) ? r - 1 : 0);
    unsigned* cntMine = wsu + CNT_OFFW + b * GB + r;

    float D0 = INF, D1 = INF;
    float up0prev = INF;
    const float dg0init = (l == 0) ? ((r == 0) ? 0.0f : INF) : INF;
    __syncthreads();

    // prologue: acquire + stage chunk 0 into TLb[0]
    if (r > 0) {
        while (__hip_atomic_load(cntPrev, __ATOMIC_ACQUIRE,
                                 __HIP_MEMORY_SCOPE_AGENT) < 1u)
            __builtin_amdgcn_s_sleep(1);
        if (l < 32)
            TLb[0][l] = __int_as_float(__hip_atomic_load(
                (const unsigned*)&browPrev[l],
                __ATOMIC_RELAXED, __HIP_MEMORY_SCOPE_AGENT));
        __syncthreads();
    }

    // tx/ty double-buffer: cur = steps u0..u0+7, nxt prefetched a block ahead
    float curx[8], cury[8], nxtx[8], nxty[8];
    #pragma unroll
    for (int k = 0; k < 8; ++k) {
        curx[k] = txA[63 + k - l]; cury[k] = tyA[63 + k - l];
    }

    for (int c = 0; c < SB; ++c) {
        #pragma unroll
        for (int m = 0; m < 4; ++m) {
            const int u0 = 32 * c + 8 * m;
            // batch-prefetch next block (steps u0+8..u0+15) -- off the chain
            #pragma unroll
            for (int k = 0; k < 8; ++k) {
                nxtx[k] = txA[63 + (u0 + 8 + k) - l];
                nxty[k] = tyA[63 + (u0 + 8 + k) - l];
            }
            const float4 T4a = *(const float4*)&TLb[c & 1][8 * m];
            const float4 T4b = *(const float4*)&TLb[c & 1][8 * m + 4];
            const float Tv[8] = {T4a.x, T4a.y, T4a.z, T4a.w,
                                 T4b.x, T4b.y, T4b.z, T4b.w};
            unsigned word = 0;
            #pragma unroll
            for (int k = 0; k < 8; ++k) {
                const int u = u0 + k;
                const int jq = u - l;
                const bool act = (jq >= 0) && (jq < MM);
                const float sh = wave_shr1(D1);
                const float up0 = (l == 0) ? Tv[k] : sh;
                const float dg0 = (jq == 0) ? dg0init : up0prev;
                const float tx = curx[k], ty = cury[k];
                // cell (row 2l): math identical to proven kernel (absmax=0)
                const float dx0 = px0 - tx, dy0 = py0 - ty;
                const float c0 = __builtin_amdgcn_sqrtf(dx0 * dx0 + dy0 * dy0);
                const float mn0 = fminf(dg0, fminf(up0, D0));
                const float D0n = c0 + mn0;
                const unsigned m0 = (mn0 == dg0) ? 0u : ((mn0 == up0) ? 1u : 2u);
                // cell (row 2l+1)
                const float dg1 = D0;
                const float dx1 = px1 - tx, dy1 = py1 - ty;
                const float c1 = __builtin_amdgcn_sqrtf(dx1 * dx1 + dy1 * dy1);
                const float mn1 = fminf(dg1, fminf(D0n, D1));
                const float D1n = c1 + mn1;
                const unsigned m1 = (mn1 == dg1) ? 0u : ((mn1 == D0n) ? 1u : 2u);
                word |= (m0 | (m1 << 2)) << (4 * k);
                if (act) { D0 = D0n; D1 = D1n; }
                up0prev = up0;
                if (l == 63 && act) botL[jq & 63] = D1n;
            }
            decBand[(u0 >> 3) * 64 + l] = word;
            #pragma unroll
            for (int k = 0; k < 8; ++k) { curx[k] = nxtx[k]; cury[k] = nxty[k]; }
        }
        // publish chunk c-2 (cols 32(c-2)..+31): lane63 finished col 32c-32
        // by end of this superblock, so chunk c-2 is complete.
        if (r < GB - 1 && c >= 2) {
            const int ch = c - 2;
            if (l < 32)
                __hip_atomic_store((unsigned*)&browMine[32 * ch + l],
                    __float_as_uint(botL[(32 * ch + l) & 63]),
                    __ATOMIC_RELAXED, __HIP_MEMORY_SCOPE_AGENT);
            __threadfence();
            if (l == 0)
                __hip_atomic_store(cntMine, (unsigned)(ch + 1),
                                   __ATOMIC_RELEASE, __HIP_MEMORY_SCOPE_AGENT);
        }
        // acquire + stage chunk c+1 (first used at step 32(c+1))
        const int k1 = c + 1;
        if (r > 0 && k1 <= 31) {
            while (__hip_atomic_load(cntPrev, __ATOMIC_ACQUIRE,
                                     __HIP_MEMORY_SCOPE_AGENT) < (unsigned)(k1 + 1))
                __builtin_amdgcn_s_sleep(1);
            if (l < 32)
                TLb[k1 & 1][l] = __int_as_float(__hip_atomic_load(
                    (const unsigned*)&browPrev[32 * k1 + l],
                    __ATOMIC_RELAXED, __HIP_MEMORY_SCOPE_AGENT));
        }
    }
}

// ---- Backtrack + loss: 32 blocks x 256 threads (R5-proven walk, new layout) -
// Word for cell (i,j): band r=i>>7, lane ll=(i&127)>>1, step ss=ll+j;
// widx = r*BAND_WORDS + (ss>>3)*64 + ll; bit = (ss&7)*4 + (i&1)*2.
__global__ __launch_bounds__(256, 1) void dtw_bt(
    const float* __restrict__ preds, const float* __restrict__ targs,
    const float* __restrict__ subcoef, const unsigned* __restrict__ wsu,
    float* __restrict__ out)
{
    const int b = blockIdx.x, t = threadIdx.x;
    __shared__ float pxA[NN], pyA[NN], txA[MM], tyA[MM];   // 16 KB
    __shared__ unsigned path[2048];                        // 8 KB
    __shared__ int sN;
    __shared__ float wsum[4];

    for (int it = 0; it < 4; ++it) {
        const int idx = it * 256 + t;
        const float4 p4 = ((const float4*)preds)[(size_t)b * NN + idx];
        pxA[idx] = p4.x; pyA[idx] = p4.y;
        const float4 t4 = ((const float4*)targs)[(size_t)b * MM + idx];
        txA[idx] = t4.x; tyA[idx] = t4.y;
    }
    __syncthreads();

    if (t == 0) {
        const unsigned* __restrict__ decB = wsu + (size_t)b * BAT_WORDS3;
        int i = NN - 1, j = MM - 1, n = 0;
        int cwidx = -1; unsigned cw = 0;
        while (true) {
            path[n++] = ((unsigned)i << 16) | (unsigned)j;
            if ((i | j) == 0) break;
            const int ll = (i & 127) >> 1;
            const int ss = ll + j;
            const int widx = (i >> 7) * BAND_WORDS + (ss >> 3) * 64 + ll;
            if (widx != cwidx) { cw = decB[widx]; cwidx = widx; }
            const unsigned m = (cw >> ((ss & 7) * 4 + (i & 1) * 2)) & 3u;
            i -= (m != 2u); j -= (m != 1u);
        }
        sN = n;
    }
    __syncthreads();

    const float sc0 = subcoef[0], sc1 = subcoef[1];
    const int n = sN;
    float acc = 0.0f;
    for (int p = t; p < n; p += 256) {
        const unsigned e = path[p];
        const int i = (int)(e >> 16), j = (int)(e & 0xffffu);
        acc += fabsf(pxA[i] - txA[j]) * sc0 + fabsf(pyA[i] - tyA[j]) * sc1;
    }
    #pragma unroll
    for (int o = 32; o > 0; o >>= 1) acc += __shfl_down(acc, o);
    if ((t & 63) == 0) wsum[t >> 6] = acc;
    __syncthreads();
    if (t == 0) atomicAdd(out, (wsum[0] + wsum[1]) + (wsum[2] + wsum[3]));
}

// =================== Legacy proven path (557us, needs 8MB) ===================
__device__ inline void bt_walk4(const unsigned* __restrict__ sdec, int roff,
                                int iLow, int& i, int& j, int& n,
                                unsigned* __restrict__ path)
{
    int ri = i >> 2, jc = j >> 2;
    unsigned w = sdec[(ri - roff) * 256 + jc];
    while (true) {
        const int base = (ri - roff) * 256 + jc;
        const unsigned wl = sdec[(jc > 0)    ? base - 1   : base];
        const unsigned wu = sdec[(ri > roff) ? base - 256 : base];
        const unsigned wd = sdec[(ri > roff && jc > 0) ? base - 257 : base];
        bool done = false, susp = false;
        while (true) {
            path[n++] = ((unsigned)i << 16) | (unsigned)j;
            if ((i | j) == 0) { done = true; break; }
            const unsigned m = (w >> (((i & 3) * 4 + (j & 3)) * 2)) & 3u;
            i -= (m != 2u); j -= (m != 1u);
            if (i < iLow) { susp = true; break; }
            if ((i >> 2) != ri || (j >> 2) != jc) break;
        }
        if (done || susp) break;
        const int nri = i >> 2, njc = j >> 2;
        w = (nri == ri) ? wl : ((njc == jc) ? wu : wd);
        ri = nri; jc = njc;
    }
}

#define RRL 4
#define CCL 4
#define LANES 64
#define NWAVE 4
#define TPBL (MM / 4)
#define NSUP (TPBL + LANES - 1)
#define LAG 72
#define TOTL (NSUP + (NWAVE - 1) * LAG)
#define DEPTH 32

__global__ __launch_bounds__(256, 1) void dtw_fused_legacy(
    const float* __restrict__ preds, const float* __restrict__ targs,
    const float* __restrict__ subcoef, unsigned* __restrict__ dec,
    float* __restrict__ out)
{
    const int b = blockIdx.x, t = threadIdx.x;
    const int l = t & 63, w = t >> 6;
    const float INF = __builtin_inff();

    __shared__ float pxA[NN], pyA[NN], txA[MM], tyA[MM];
    __shared__ float4 ring[NWAVE - 1][DEPTH];
    __shared__ unsigned sdec[128 * 256];
    __shared__ unsigned path[LPATH + 1];
    __shared__ int sI, sJ, sN;
    __shared__ float wsum[NWAVE];

    for (int it = 0; it < NN / 256; ++it) {
        const int idx = it * 256 + t;
        const float4 p4 = ((const float4*)preds)[(size_t)b * NN + idx];
        pxA[idx] = p4.x; pyA[idx] = p4.y;
        const float4 t4 = ((const float4*)targs)[(size_t)b * MM + idx];
        txA[idx] = t4.x; tyA[idx] = t4.y;
    }
    __syncthreads();

    const int i0 = (w << 8) + (l << 2);
    const float4 px4 = ((const float4*)pxA)[i0 >> 2];
    const float4 py4 = ((const float4*)pyA)[i0 >> 2];
    const float px[RRL] = {px4.x, px4.y, px4.z, px4.w};
    const float py[RRL] = {py4.x, py4.y, py4.z, py4.w};
    unsigned* __restrict__ decW =
        dec + (size_t)b * DEC_WORDS_PER_BATCH + ((size_t)w << 14) + (size_t)l;

    float Dp[RRL], Dbot[CCL], bv[CCL];
    #pragma unroll
    for (int r = 0; r < RRL; ++r) Dp[r] = INF;
    #pragma unroll
    for (int c = 0; c < CCL; ++c) { Dbot[c] = INF; bv[c] = INF; }
    float bndRet = (w == 0 && l == 0) ? 0.0f : INF;
    float4 gcur = make_float4(INF, INF, INF, INF);
    float4 tx4 = ((const float4*)txA)[0], ty4 = ((const float4*)tyA)[0];
    const float4* __restrict__ ringR = ring[(w > 0) ? (w - 1) : 0];

    for (int u = 0; u < TOTL; ++u) {
        const int ul = u - LAG * w;
        if (l == 0) {
            const bool gb = (w > 0) && (ul >= 0) && (ul < TPBL);
            bv[0] = gb ? gcur.x : INF; bv[1] = gb ? gcur.y : INF;
            bv[2] = gb ? gcur.z : INF; bv[3] = gb ? gcur.w : INF;
        }
        const bool act = (ul >= l) && (ul < l + TPBL);
        if (act) {
            const float cx[CCL] = {tx4.x, tx4.y, tx4.z, tx4.w};
            const float cy[CCL] = {ty4.x, ty4.y, ty4.z, ty4.w};
            float cost[RRL][CCL];
            #pragma unroll
            for (int c = 0; c < CCL; ++c)
                #pragma unroll
                for (int r = 0; r < RRL; ++r) {
                    const float dx = px[r] - cx[c], dy = py[r] - cy[c];
                    cost[r][c] = __builtin_amdgcn_sqrtf(dx * dx + dy * dy);
                }
            unsigned word = 0;
            #pragma unroll
            for (int c = 0; c < CCL; ++c) {
                float up = bv[c];
                float dg = (c == 0) ? bndRet : bv[c - 1];
                #pragma unroll
                for (int r = 0; r < RRL; ++r) {
                    const float lf = Dp[r];
                    const unsigned m = (dg <= up && dg <= lf) ? 0u
                                     : ((up <= lf) ? 1u : 2u);
                    const float D = cost[r][c] + fminf(dg, fminf(up, lf));
                    word |= m << ((r * 4 + c) * 2);
                    dg = lf; up = D; Dp[r] = D;
                }
                Dbot[c] = up;
            }
            decW[(ul & 255) << 6] = word;
            if (l == LANES - 1 && w < NWAVE - 1)
                ring[w][ul & (DEPTH - 1)] =
                    make_float4(Dbot[0], Dbot[1], Dbot[2], Dbot[3]);
        }
        bndRet = bv[CCL - 1];
        #pragma unroll
        for (int c = 0; c < CCL; ++c) bv[c] = __shfl_up(Dbot[c], 1);
        const int un = ul + 1;
        if (un >= l && un < l + TPBL) {
            const int jn = CCL * (un - l);
            tx4 = ((const float4*)txA)[jn >> 2];
            ty4 = ((const float4*)tyA)[jn >> 2];
        }
        if (w > 0 && un >= 0 && un < TPBL)
            gcur = ringR[(un + 63) & (DEPTH - 1)];
        if ((u & 7) == 7) __syncthreads();
    }

    __threadfence_block();
    __syncthreads();

    const unsigned* __restrict__ decB = dec + (size_t)b * DEC_WORDS_PER_BATCH;
    {
        const uint4* g4 = (const uint4*)(decB + 32768);
        for (int k = t; k < 8192; k += 256) {
            const uint4 v = g4[k];
            const int kb = k << 2;
            const int wv = kb >> 14;
            const int rem = kb & 16383;
            const int q = rem >> 6;
            const int lb = rem & 63;
            const unsigned wd[4] = {v.x, v.y, v.z, v.w};
            #pragma unroll
            for (int e = 0; e < 4; ++e) {
                const int ll = lb + e;
                const int row = (wv << 6) + ll;
                const int jc = (q - ll) & 255;
                sdec[(row << 8) + jc] = wd[e];
            }
        }
    }
    __syncthreads();
    if (t == 0) {
        int i = NN - 1, j = MM - 1, n = 0;
        bt_walk4(sdec, 128, 512, i, j, n, path);
        sI = i; sJ = j; sN = n;
    }
    __syncthreads();
    {
        const uint4* g4 = (const uint4*)decB;
        for (int k = t; k < 8192; k += 256) {
            const uint4 v = g4[k];
            const int kb = k << 2;
            const int wv = kb >> 14;
            const int rem = kb & 16383;
            const int q = rem >> 6;
            const int lb = rem & 63;
            const unsigned wd[4] = {v.x, v.y, v.z, v.w};
            #pragma unroll
            for (int e = 0; e < 4; ++e) {
                const int ll = lb + e;
                const int row = (wv << 6) + ll;
                const int jc = (q - ll) & 255;
                sdec[(row << 8) + jc] = wd[e];
            }
        }
    }
    __syncthreads();
    if (t == 0) {
        int i = sI, j = sJ, n = sN;
        bt_walk4(sdec, 0, 0, i, j, n, path);
        sN = n;
    }
    __syncthreads();

    const float sc0 = subcoef[0], sc1 = subcoef[1];
    const int n = sN;
    float acc = 0.0f;
    for (int p = t; p < n; p += 256) {
        const unsigned e = path[p];
        const int i = (int)(e >> 16), j = (int)(e & 0xffffu);
        acc += fabsf(pxA[i] - txA[j]) * sc0 + fabsf(pyA[i] - tyA[j]) * sc1;
    }
    #pragma unroll
    for (int o = 32; o > 0; o >>= 1) acc += __shfl_down(acc, o);
    if ((t & 63) == 0) wsum[t >> 6] = acc;
    __syncthreads();
    if (t == 0) atomicAdd(out, (wsum[0] + wsum[1]) + (wsum[2] + wsum[3]));
}

// ------------- Fallback (only if ws too small for everything) ----------------
__global__ __launch_bounds__(256) void dtw_fallback(
    const float* __restrict__ preds, const float* __restrict__ targs,
    const float* __restrict__ subcoef, unsigned* __restrict__ dec,
    float* __restrict__ out)
{
    const int b = blockIdx.x;
    const int t = threadIdx.x;
    const float INF = __builtin_inff();
    __shared__ float px[NN], py[NN];
    __shared__ float txy[2 * MM];
    __shared__ float bbuf[2][256];

    for (int it = 0; it < NN / 256; ++it) {
        const int idx = it * 256 + t;
        const float4 p4 = ((const float4*)preds)[(size_t)b * NN + idx];
        px[idx] = p4.x; py[idx] = p4.y;
        const float4 t4 = ((const float4*)targs)[(size_t)b * MM + idx];
        txy[2 * idx] = t4.x; txy[2 * idx + 1] = t4.y;
    }
    bbuf[0][t] = INF; bbuf[1][t] = INF;
    __syncthreads();

    float pxr[4], pyr[4], Dp[4];
    #pragma unroll
    for (int r = 0; r < 4; ++r) {
        pxr[r] = px[4 * t + r]; pyr[r] = py[4 * t + r]; Dp[r] = INF;
    }
    float dgB = (t == 0) ? 0.0f : INF;
    unsigned packed = 0;
    unsigned* decB = dec + (size_t)b * 65536;
    for (int s = 0; s < MM + 255; ++s) {
        const int j = s - t;
        const float upB = (t == 0) ? INF : bbuf[(s + 1) & 1][t - 1];
        if (j >= 0 && j < MM) {
            const float txj = txy[2 * j], tyj = txy[2 * j + 1];
            float up = upB, dg = dgB;
            unsigned mbits = 0;
            #pragma unroll
            for (int r = 0; r < 4; ++r) {
                const float dx = pxr[r] - txj, dy = pyr[r] - tyj;
                const float c = sqrtf(dx * dx + dy * dy);
                const float lf = Dp[r];
                const unsigned m = (dg <= up && dg <= lf) ? 0u
                                 : ((up <= lf) ? 1u : 2u);
                mbits |= m << (r * 8 + (j & 3) * 2);
                const float Dc = c + fminf(up, fminf(dg, lf));
                dg = lf; up = Dc; Dp[r] = Dc;
            }
            packed |= mbits;
            if ((j & 3) == 3) { decB[(unsigned)t * 256 + (j >> 2)] = packed; packed = 0; }
            bbuf[s & 1][t] = Dp[3];
        }
        dgB = upB;
        __syncthreads();
    }
    __threadfence_block();
    __syncthreads();
    if (t == 0) {
        const float sc0 = subcoef[0], sc1 = subcoef[1];
        int i = NN - 1, jj = MM - 1;
        float loss = 0.0f;
        int ti = i >> 2, tj = jj >> 2;
        unsigned wv = decB[ti * 256 + tj];
        while (true) {
            const int tjl = (tj > 0) ? tj - 1 : 0;
            const int til = (ti > 0) ? ti - 1 : 0;
            const unsigned wl = decB[ti * 256 + tjl];
            const unsigned wu = decB[til * 256 + tj];
            const unsigned wd = decB[til * 256 + tjl];
            bool done = false;
            while (true) {
                loss += fabsf(px[i] - txy[2 * jj]) * sc0
                      + fabsf(py[i] - txy[2 * jj + 1]) * sc1;
                if ((i | jj) == 0) { done = true; break; }
                const unsigned m = (wv >> (((i & 3) * 4 + (jj & 3)) * 2)) & 3u;
                i -= (m != 2u); jj -= (m != 1u);
                if ((i >> 2) != ti || (jj >> 2) != tj) break;
            }
            if (done) break;
            const int nti = i >> 2, ntj = jj >> 2;
            wv = (nti == ti) ? wl : ((ntj == tj) ? wu : wd);
            ti = nti; tj = ntj;
        }
        atomicAdd(out, loss);
    }
}

extern "C" void kernel_launch(void* const* d_in, const int* in_sizes, int n_in,
                              void* d_out, int out_size, void* d_ws, size_t ws_size,
                              hipStream_t stream) {
    const float* preds   = (const float*)d_in[0];
    const float* targs   = (const float*)d_in[1];
    const float* subcoef = (const float*)d_in[2];
    float* out = (float*)d_out;

    if (ws_size >= REQ_WS3) {
        unsigned* wsu = (unsigned*)d_ws;
        init4<<<1, 256, 0, stream>>>(wsu, out);
        dtw_dp3<<<BATCH * GB, 64, 0, stream>>>(preds, targs, wsu);
        dtw_bt<<<BATCH, 256, 0, stream>>>(preds, targs, subcoef, wsu, out);
    } else if (ws_size >= REQ_WS) {
        unsigned* dec = (unsigned*)d_ws;
        init_kernel<<<1, 1, 0, stream>>>(out);
        dtw_fused_legacy<<<BATCH, 256, 0, stream>>>(preds, targs, subcoef, dec, out);
    } else {
        unsigned* dec = (unsigned*)d_ws;
        init_kernel<<<1, 1, 0, stream>>>(out);
        dtw_fallback<<<BATCH, 256, 0, stream>>>(preds, targs, subcoef, dec, out);
    }
}